// Round 4
// baseline (142.549 us; speedup 1.0000x reference)
//
#include <hip/hip_runtime.h>

// EdgeConv with KNN graph: B=8, N=4096, D=3, E=64, K=32.
// === R20: R19 geometry (1024-thr blocks, 32 waves/CU) + relaxed reg cap ===
// R19 post-mortem: occupancy theory CONFIRMED (51->62%) but launch_bounds
// (1024,8) hard-capped VGPR at 64 and the allocator tipped into wholesale
// pk[] demotion (VGPR_Count 40->32 collapse; FETCH 1.7->12.9MB, WRITE
// 8->55MB scratch tripwire). Spill cost ~cancelled the occupancy win
// (86.4 -> 84.9 only).
// R20 single variable vs R19: __launch_bounds__(1024, 6) -> cap ~85 VGPRs
// (same cap the verified R16 body compiled at 40 under). Actual usage ~40
// <= 64 keeps 8 waves/SIMD achievable in HW; LDS 52KB -> 2 blocks/CU
// (16 waves each) = 32 waves/CU; 1024 blocks = exactly 2 full rounds.
// PASS SIGNAL: VGPR_Count ~40, FETCH ~1.5MB, WRITE ~8MB.
// Predicted: Occupancy ~70-80, VALUBusy ~80-87, dispatch ~72-77 us.
// RISK: allocator uses >64 VGPR -> 4 waves/SIMD -> regress ~95 us; then
// next round pins cap + manual pressure cuts.
// Unchanged: sweep math (BIT-IDENTICAL packed fmaf chain, self-dist == 0),
//  u16 monotone-truncation keys, PER-POINT sampled threshold (bitonic of
//  64 lane-minima, readlane 32), ballot probes (gallop/bisect), ONE
//  index-only compaction, exact-fp32 partial bitonic, lower-index
//  tie-break == jax.lax.top_k, readlane epilogue, fresh per-point H.
// SPILL DISCIPLINE (R2/R3): every loop touching pk[] FULLY unrolled, ONE
// textual instance of each. TRIPWIRE: FETCH>6MB or VGPR_Count<40.

#define NPTS 4096
#define KNN  32

#define WFENCE() __asm__ volatile("s_waitcnt lgkmcnt(0)" ::: "memory")

typedef unsigned short u16x2 __attribute__((ext_vector_type(2)));
typedef float          f32x2 __attribute__((ext_vector_type(2)));

__device__ __forceinline__ unsigned lane_prefix(unsigned long long m) {
    return __builtin_amdgcn_mbcnt_hi((unsigned)(m >> 32),
           __builtin_amdgcn_mbcnt_lo((unsigned)m, 0u));
}
__device__ __forceinline__ unsigned pk_min_u16(unsigned a, unsigned b) {
    return __builtin_bit_cast(unsigned, __builtin_elementwise_min(
        __builtin_bit_cast(u16x2, a), __builtin_bit_cast(u16x2, b)));
}
// lo16 = top16(d0), hi16 = top16(d1)
__device__ __forceinline__ unsigned pack_keys(float d0, float d1) {
    return __builtin_amdgcn_perm(__builtin_bit_cast(unsigned, d1),
                                 __builtin_bit_cast(unsigned, d0), 0x07060302u);
}

__global__ __launch_bounds__(1024, 6)
void edgeconv_knn_kernel(const float* __restrict__ x,
                         const float* __restrict__ theta_w,
                         const float* __restrict__ theta_b,
                         const float* __restrict__ phi_w,
                         const float* __restrict__ phi_b,
                         float* __restrict__ out)
{
    __shared__ float    s_x[NPTS];         // 16 KB per plane (48 KB total)
    __shared__ float    s_y[NPTS];
    __shared__ float    s_z[NPTS];
    __shared__ unsigned s_pool[16][64];    // 4 KB: per-wave survivor indices

    const int tid  = threadIdx.x;
    const int wv   = tid >> 6;             // 16 waves
    const int lane = tid & 63;

    const int b  = blockIdx.x >> 7;        // 128 blocks per batch
    const int i0 = (blockIdx.x & 127) << 5;// 32 points per block (2 per wave)

    // lane == output channel e
    const float tw0 = theta_w[lane];
    const float tw1 = theta_w[64 + lane];
    const float tw2 = theta_w[128 + lane];
    const float tbv = theta_b[lane];
    const float pw0 = phi_w[lane];
    const float pw1 = phi_w[64 + lane];
    const float pw2 = phi_w[128 + lane];
    const float pbv = phi_b[lane];

    const float* xb = x + (size_t)b * NPTS * 3;
    for (int p = tid; p < NPTS; p += 1024) {
        s_x[p] = xb[p * 3 + 0];
        s_y[p] = xb[p * 3 + 1];
        s_z[p] = xb[p * 3 + 2];
    }
    __syncthreads();

    for (int r = 0; r < 2; ++r) {
        const int i = i0 + wv * 2 + r;
        const float px = s_x[i], py = s_y[i], pz = s_z[i];
        const float sqi = fmaf(pz, pz, fmaf(py, py, px * px));
        const f32x2 PX2 = {px, px}, PY2 = {py, py}, PZ2 = {pz, pz};
        const f32x2 SQI2 = {sqi, sqi};
        const f32x2 N2   = {-2.0f, -2.0f};
        const f32x2 Z02  = {0.0f, 0.0f};

        // ---- sweep: lane owns candidates j = 256*t + 4*lane + {0..3} ----
        // slot s=0..63 -> j = ((s>>2)<<8) + (lane<<2) + (s&3)
        unsigned pk[32];
        unsigned pmin = 0xFFFFFFFFu;
        #pragma unroll
        for (int t = 0; t < 16; ++t) {
            const int jb = (t << 8) + (lane << 2);
            const float4 QX = *(const float4*)&s_x[jb];
            const float4 QY = *(const float4*)&s_y[jb];
            const float4 QZ = *(const float4*)&s_z[jb];
            const f32x2 X0 = {QX.x, QX.y}, X1 = {QX.z, QX.w};
            const f32x2 Y0 = {QY.x, QY.y}, Y1 = {QY.z, QY.w};
            const f32x2 Zc0 = {QZ.x, QZ.y}, Zc1 = {QZ.z, QZ.w};
            // sq_j with the identical chain: fma(z,z, fma(y,y, x*x))
            const f32x2 S0 = __builtin_elementwise_fma(Zc0, Zc0,
                             __builtin_elementwise_fma(Y0, Y0, X0 * X0));
            const f32x2 S1 = __builtin_elementwise_fma(Zc1, Zc1,
                             __builtin_elementwise_fma(Y1, Y1, X1 * X1));
            // dot with the identical chain: fma(pz,qz, fma(py,qy, px*qx))
            const f32x2 dt0 = __builtin_elementwise_fma(PZ2, Zc0,
                              __builtin_elementwise_fma(PY2, Y0, PX2 * X0));
            const f32x2 dt1 = __builtin_elementwise_fma(PZ2, Zc1,
                              __builtin_elementwise_fma(PY2, Y1, PX2 * X1));
            f32x2 d0 = __builtin_elementwise_fma(N2, dt0, SQI2 + S0);
            f32x2 d1 = __builtin_elementwise_fma(N2, dt1, SQI2 + S1);
            d0 = __builtin_elementwise_max(d0, Z02);
            d1 = __builtin_elementwise_max(d1, Z02);
            pk[2 * t]     = pack_keys(d0.x, d0.y);
            pk[2 * t + 1] = pack_keys(d1.x, d1.y);
            pmin = pk_min_u16(pmin, pk[2 * t]);
            pmin = pk_min_u16(pmin, pk[2 * t + 1]);
        }
        unsigned mn = min(pmin & 0xFFFFu, pmin >> 16);   // per-lane min (u16)

        // ---- PER-POINT bitonic sort of 64 lane-minima -> sampled threshold
        #pragma unroll
        for (int k = 2; k <= 64; k <<= 1) {
            #pragma unroll
            for (int jj = k >> 1; jj >= 1; jj >>= 1) {
                const unsigned o = (unsigned)__shfl_xor((int)mn, jj, 64);
                const bool wantmin = (((lane & k) == 0) == ((lane & jj) == 0));
                const bool less = (mn < o);
                if (less != wantmin) mn = o;
            }
        }
        unsigned H = (unsigned)__builtin_amdgcn_readlane((int)mn, 32);

        // wave-uniform count of u16 keys strictly below T (ballot -> scalar)
        auto cnt_lt = [&](unsigned T) -> unsigned {
            unsigned c = 0;
            #pragma unroll
            for (int k2 = 0; k2 < 32; ++k2) {
                c += (unsigned)__popcll(__ballot((pk[k2] & 0xFFFFu) < T));
                c += (unsigned)__popcll(__ballot((pk[k2] >> 16)     < T));
            }
            return c;
        };

        // ---- threshold search in u16 key space ----
        unsigned L = 0u;
        unsigned c = cnt_lt(H);
        if (c < KNN) {                       // raise by octaves (exp LSB = 0x80)
            unsigned step = 0x80u;
            do {
                unsigned Hn = H + step;
                if (Hn > 0xFFFFu) Hn = 0xFFFFu;
                L = H; H = Hn; step <<= 1;
                c = cnt_lt(H);
            } while (c < KNN);
        }
        while (c > 64u && (H - L) > 1u) {
            const unsigned M  = L + ((H - L) >> 1);
            const unsigned cm = cnt_lt(M);
            if (cm >= KNN) { H = M; c = cm; } else { L = M; }
        }

        // ---- compaction: survivor indices only (ballot + mbcnt) ----
        WFENCE();                            // prior pool consumers done
        unsigned base = 0;
        #pragma unroll
        for (int s = 0; s < 64; ++s) {
            const unsigned kk = (s & 1) ? (pk[s >> 1] >> 16)
                                        : (pk[s >> 1] & 0xFFFFu);
            const bool pred = kk < H;
            const unsigned long long bm = __ballot(pred);
            if (bm) {
                if (pred) {
                    const unsigned pos = base + lane_prefix(bm);
                    if (pos < 64u)
                        s_pool[wv][pos] =
                            (unsigned)(((s >> 2) << 8) + (lane << 2) + (s & 3));
                }
                base += (unsigned)__popcll(bm);
            }
        }
        WFENCE();
        const unsigned m = base < 64u ? base : 64u;   // m >= 32 guaranteed

        // ---- exact fp32 keys for pool members (identical op chain) ----
        unsigned myk = 0xFFFFFFFFu;
        unsigned myj = 0u;                   // sentinel, never selected (m>=32)
        if ((unsigned)lane < m) {
            myj = s_pool[wv][lane];
            const float qx = s_x[myj], qy = s_y[myj], qz = s_z[myj];
            const float sqj = fmaf(qz, qz, fmaf(qy, qy, qx * qx));
            const float dt  = fmaf(pz, qz, fmaf(py, qy, px * qx));
            float d = fmaf(-2.0f, dt, sqi + sqj);
            d = fmaxf(d, 0.0f);
            myk = __builtin_bit_cast(unsigned, d);
        }

        // ---- partial bitonic: 32-sorts + one merge -> bottom-32 unordered ----
        #pragma unroll
        for (int k = 2; k <= 32; k <<= 1) {
            #pragma unroll
            for (int jj = k >> 1; jj >= 1; jj >>= 1) {
                const unsigned ok = (unsigned)__shfl_xor((int)myk, jj, 64);
                const unsigned oj = (unsigned)__shfl_xor((int)myj, jj, 64);
                const bool wantmin = (((lane & k) == 0) == ((lane & jj) == 0));
                const bool less = (myk < ok) || (myk == ok && myj < oj);
                if (less != wantmin) { myk = ok; myj = oj; }
            }
        }
        {   // k=64, jj=32: lanes 0..31 <- the 32 smallest (unordered)
            const unsigned ok = (unsigned)__shfl_xor((int)myk, 32, 64);
            const unsigned oj = (unsigned)__shfl_xor((int)myj, 32, 64);
            const bool wantmin = ((lane & 32) == 0);
            const bool less = (myk < ok) || (myk == ok && myj < oj);
            if (less != wantmin) { myk = ok; myj = oj; }
        }

        // ---- epilogue: lane = channel e; max over the 32 selected ----
        float dx = 0.f, dy = 0.f, dz = 0.f;
        if (lane < KNN) {
            dx = s_x[myj] - px; dy = s_y[myj] - py; dz = s_z[myj] - pz;
        }
        const float basev = tbv + pbv + fmaf(pw2, pz, fmaf(pw1, py, pw0 * px));
        float mx = -3.0e38f;
        #pragma unroll
        for (int t = 0; t < KNN; ++t) {
            const float ndx = __builtin_bit_cast(float, __builtin_amdgcn_readlane(__builtin_bit_cast(int, dx), t));
            const float ndy = __builtin_bit_cast(float, __builtin_amdgcn_readlane(__builtin_bit_cast(int, dy), t));
            const float ndz = __builtin_bit_cast(float, __builtin_amdgcn_readlane(__builtin_bit_cast(int, dz), t));
            const float proj = fmaf(tw2, ndz, fmaf(tw1, ndy, tw0 * ndx));
            mx = fmaxf(mx, proj);
        }
        out[(((size_t)b * NPTS + (size_t)i) << 6) + lane] = mx + basev;
    }
}

extern "C" void kernel_launch(void* const* d_in, const int* in_sizes, int n_in,
                              void* d_out, int out_size, void* d_ws, size_t ws_size,
                              hipStream_t stream) {
    const float* x  = (const float*)d_in[0];
    const float* tw = (const float*)d_in[1];
    const float* tb = (const float*)d_in[2];
    const float* pw = (const float*)d_in[3];
    const float* pb = (const float*)d_in[4];
    float* out = (float*)d_out;

    dim3 grid(8 * 128);   // 1024 blocks x 32 pts; 2 blocks/CU, 32 waves/CU
    dim3 block(1024);
    hipLaunchKernelGGL(edgeconv_knn_kernel, grid, block, 0, stream,
                       x, tw, tb, pw, pb, out);
}

// Round 5
// 135.022 us; speedup vs baseline: 1.0557x; 1.0557x over previous
//
#include <hip/hip_runtime.h>

// EdgeConv with KNN graph: B=8, N=4096, D=3, E=64, K=32.
// === R21: R16 geometry+body EXACTLY (86.4 us verified) + DPP lane-XORs ===
// R20 post-mortem: 1024-thr blocks -> only ~1 block/CU resident (occ 43%,
// VALU 64%, 91.9 us). Geometry arc CLOSED: 512-thr/2048-block is best.
// R21 theory: per point, DS pipe ~950 cyc vs VALU ~1130 cyc -> co-saturated;
// bitonic networks are shfl(ds_bpermute, ~25-30cy latency)->cmp->cndmask
// SERIAL chains (21 + 32 stages). Convert xor1/xor2/xor8 to DPP on the
// VALU pipe (bit-exact lane permutation):
//   xor1 = quad_perm[1,0,3,2] (0xB1), xor2 = quad_perm[2,3,0,1] (0x4E),
//   xor8 = row_ror:8 (0x128; ror8 == xor8 within a 16-lane row).
// xor4/16/32 keep __shfl_xor (no classic-DPP encoding). 36 of 53 shuffle
// ops move off the DS pipe; per-stage chain latency ~25 -> ~4 cyc.
// All bitonics run at full exec (lane<m guard closed) -> masks 0xF safe.
// Predicted: dur 86.4 -> 77-81 us, VALUBusy 73-78%, VGPR ~40, occ ~51%.
// Null (86 +/- 2) => shuffle latency already TLP-hidden => next: cut
// instruction count (single-site speculative compact).
// Unchanged: sweep math (BIT-IDENTICAL packed fmaf chain, self-dist == 0),
//  u16 monotone-truncation keys, PER-POINT sampled threshold, ballot
//  probes (gallop/bisect), ONE index-only compaction, exact-fp32 partial
//  bitonic, lower-index tie-break == jax.lax.top_k, readlane epilogue.
// SPILL DISCIPLINE (R2/R3): every loop touching pk[] FULLY unrolled, ONE
// textual instance of each; (512,6) 85-VGPR budget. TRIPWIRE: FETCH>6MB.

#define NPTS 4096
#define KNN  32

#define WFENCE() __asm__ volatile("s_waitcnt lgkmcnt(0)" ::: "memory")

typedef unsigned short u16x2 __attribute__((ext_vector_type(2)));
typedef float          f32x2 __attribute__((ext_vector_type(2)));

__device__ __forceinline__ unsigned lane_prefix(unsigned long long m) {
    return __builtin_amdgcn_mbcnt_hi((unsigned)(m >> 32),
           __builtin_amdgcn_mbcnt_lo((unsigned)m, 0u));
}
__device__ __forceinline__ unsigned pk_min_u16(unsigned a, unsigned b) {
    return __builtin_bit_cast(unsigned, __builtin_elementwise_min(
        __builtin_bit_cast(u16x2, a), __builtin_bit_cast(u16x2, b)));
}
// lo16 = top16(d0), hi16 = top16(d1)
__device__ __forceinline__ unsigned pack_keys(float d0, float d1) {
    return __builtin_amdgcn_perm(__builtin_bit_cast(unsigned, d1),
                                 __builtin_bit_cast(unsigned, d0), 0x07060302u);
}

// Lane-XOR exchange. jj in {1,2,8}: DPP on the VALU pipe (quad_perm /
// row_ror:8) -- bit-exact permutation, no DS-pipe use, ~4cy latency.
// jj in {4,16,32}: fall back to __shfl_xor (ds_bpermute).
__device__ __forceinline__ unsigned lane_xor(unsigned v, const int jj) {
    if (jj == 1)
        return (unsigned)__builtin_amdgcn_update_dpp(
            (int)v, (int)v, 0xB1, 0xF, 0xF, false);   // quad_perm [1,0,3,2]
    if (jj == 2)
        return (unsigned)__builtin_amdgcn_update_dpp(
            (int)v, (int)v, 0x4E, 0xF, 0xF, false);   // quad_perm [2,3,0,1]
    if (jj == 8)
        return (unsigned)__builtin_amdgcn_update_dpp(
            (int)v, (int)v, 0x128, 0xF, 0xF, false);  // row_ror:8 == xor8
    return (unsigned)__shfl_xor((int)v, jj, 64);
}

__global__ __launch_bounds__(512, 6)
void edgeconv_knn_kernel(const float* __restrict__ x,
                         const float* __restrict__ theta_w,
                         const float* __restrict__ theta_b,
                         const float* __restrict__ phi_w,
                         const float* __restrict__ phi_b,
                         float* __restrict__ out)
{
    __shared__ float    s_x[NPTS];         // 16 KB per plane (48 KB total)
    __shared__ float    s_y[NPTS];
    __shared__ float    s_z[NPTS];
    __shared__ unsigned s_pool[8][64];     // 2 KB: per-wave survivor indices

    const int tid  = threadIdx.x;
    const int wv   = tid >> 6;
    const int lane = tid & 63;

    const int b  = blockIdx.x >> 8;        // 256 blocks per batch
    const int i0 = (blockIdx.x & 255) << 4;// 16 points per block (2 per wave)

    // lane == output channel e
    const float tw0 = theta_w[lane];
    const float tw1 = theta_w[64 + lane];
    const float tw2 = theta_w[128 + lane];
    const float tbv = theta_b[lane];
    const float pw0 = phi_w[lane];
    const float pw1 = phi_w[64 + lane];
    const float pw2 = phi_w[128 + lane];
    const float pbv = phi_b[lane];

    const float* xb = x + (size_t)b * NPTS * 3;
    for (int p = tid; p < NPTS; p += 512) {
        s_x[p] = xb[p * 3 + 0];
        s_y[p] = xb[p * 3 + 1];
        s_z[p] = xb[p * 3 + 2];
    }
    __syncthreads();

    for (int r = 0; r < 2; ++r) {
        const int i = i0 + wv * 2 + r;
        const float px = s_x[i], py = s_y[i], pz = s_z[i];
        const float sqi = fmaf(pz, pz, fmaf(py, py, px * px));
        const f32x2 PX2 = {px, px}, PY2 = {py, py}, PZ2 = {pz, pz};
        const f32x2 SQI2 = {sqi, sqi};
        const f32x2 N2   = {-2.0f, -2.0f};
        const f32x2 Z02  = {0.0f, 0.0f};

        // ---- sweep: lane owns candidates j = 256*t + 4*lane + {0..3} ----
        // slot s=0..63 -> j = ((s>>2)<<8) + (lane<<2) + (s&3)
        unsigned pk[32];
        unsigned pmin = 0xFFFFFFFFu;
        #pragma unroll
        for (int t = 0; t < 16; ++t) {
            const int jb = (t << 8) + (lane << 2);
            const float4 QX = *(const float4*)&s_x[jb];
            const float4 QY = *(const float4*)&s_y[jb];
            const float4 QZ = *(const float4*)&s_z[jb];
            const f32x2 X0 = {QX.x, QX.y}, X1 = {QX.z, QX.w};
            const f32x2 Y0 = {QY.x, QY.y}, Y1 = {QY.z, QY.w};
            const f32x2 Zc0 = {QZ.x, QZ.y}, Zc1 = {QZ.z, QZ.w};
            // sq_j with the identical chain: fma(z,z, fma(y,y, x*x))
            const f32x2 S0 = __builtin_elementwise_fma(Zc0, Zc0,
                             __builtin_elementwise_fma(Y0, Y0, X0 * X0));
            const f32x2 S1 = __builtin_elementwise_fma(Zc1, Zc1,
                             __builtin_elementwise_fma(Y1, Y1, X1 * X1));
            // dot with the identical chain: fma(pz,qz, fma(py,qy, px*qx))
            const f32x2 dt0 = __builtin_elementwise_fma(PZ2, Zc0,
                              __builtin_elementwise_fma(PY2, Y0, PX2 * X0));
            const f32x2 dt1 = __builtin_elementwise_fma(PZ2, Zc1,
                              __builtin_elementwise_fma(PY2, Y1, PX2 * X1));
            f32x2 d0 = __builtin_elementwise_fma(N2, dt0, SQI2 + S0);
            f32x2 d1 = __builtin_elementwise_fma(N2, dt1, SQI2 + S1);
            d0 = __builtin_elementwise_max(d0, Z02);
            d1 = __builtin_elementwise_max(d1, Z02);
            pk[2 * t]     = pack_keys(d0.x, d0.y);
            pk[2 * t + 1] = pack_keys(d1.x, d1.y);
            pmin = pk_min_u16(pmin, pk[2 * t]);
            pmin = pk_min_u16(pmin, pk[2 * t + 1]);
        }
        unsigned mn = min(pmin & 0xFFFFu, pmin >> 16);   // per-lane min (u16)

        // ---- PER-POINT bitonic sort of 64 lane-minima -> sampled threshold
        #pragma unroll
        for (int k = 2; k <= 64; k <<= 1) {
            #pragma unroll
            for (int jj = k >> 1; jj >= 1; jj >>= 1) {
                const unsigned o = lane_xor(mn, jj);
                const bool wantmin = (((lane & k) == 0) == ((lane & jj) == 0));
                const bool less = (mn < o);
                if (less != wantmin) mn = o;
            }
        }
        unsigned H = (unsigned)__builtin_amdgcn_readlane((int)mn, 32);

        // wave-uniform count of u16 keys strictly below T (ballot -> scalar)
        auto cnt_lt = [&](unsigned T) -> unsigned {
            unsigned c = 0;
            #pragma unroll
            for (int k2 = 0; k2 < 32; ++k2) {
                c += (unsigned)__popcll(__ballot((pk[k2] & 0xFFFFu) < T));
                c += (unsigned)__popcll(__ballot((pk[k2] >> 16)     < T));
            }
            return c;
        };

        // ---- threshold search in u16 key space ----
        unsigned L = 0u;
        unsigned c = cnt_lt(H);
        if (c < KNN) {                       // raise by octaves (exp LSB = 0x80)
            unsigned step = 0x80u;
            do {
                unsigned Hn = H + step;
                if (Hn > 0xFFFFu) Hn = 0xFFFFu;
                L = H; H = Hn; step <<= 1;
                c = cnt_lt(H);
            } while (c < KNN);
        }
        while (c > 64u && (H - L) > 1u) {
            const unsigned M  = L + ((H - L) >> 1);
            const unsigned cm = cnt_lt(M);
            if (cm >= KNN) { H = M; c = cm; } else { L = M; }
        }

        // ---- compaction: survivor indices only (ballot + mbcnt) ----
        WFENCE();                            // prior pool consumers done
        unsigned base = 0;
        #pragma unroll
        for (int s = 0; s < 64; ++s) {
            const unsigned kk = (s & 1) ? (pk[s >> 1] >> 16)
                                        : (pk[s >> 1] & 0xFFFFu);
            const bool pred = kk < H;
            const unsigned long long bm = __ballot(pred);
            if (bm) {
                if (pred) {
                    const unsigned pos = base + lane_prefix(bm);
                    if (pos < 64u)
                        s_pool[wv][pos] =
                            (unsigned)(((s >> 2) << 8) + (lane << 2) + (s & 3));
                }
                base += (unsigned)__popcll(bm);
            }
        }
        WFENCE();
        const unsigned m = base < 64u ? base : 64u;   // m >= 32 guaranteed

        // ---- exact fp32 keys for pool members (identical op chain) ----
        unsigned myk = 0xFFFFFFFFu;
        unsigned myj = 0u;                   // sentinel, never selected (m>=32)
        if ((unsigned)lane < m) {
            myj = s_pool[wv][lane];
            const float qx = s_x[myj], qy = s_y[myj], qz = s_z[myj];
            const float sqj = fmaf(qz, qz, fmaf(qy, qy, qx * qx));
            const float dt  = fmaf(pz, qz, fmaf(py, qy, px * qx));
            float d = fmaf(-2.0f, dt, sqi + sqj);
            d = fmaxf(d, 0.0f);
            myk = __builtin_bit_cast(unsigned, d);
        }

        // ---- partial bitonic: 32-sorts + one merge -> bottom-32 unordered ----
        #pragma unroll
        for (int k = 2; k <= 32; k <<= 1) {
            #pragma unroll
            for (int jj = k >> 1; jj >= 1; jj >>= 1) {
                const unsigned ok = lane_xor(myk, jj);
                const unsigned oj = lane_xor(myj, jj);
                const bool wantmin = (((lane & k) == 0) == ((lane & jj) == 0));
                const bool less = (myk < ok) || (myk == ok && myj < oj);
                if (less != wantmin) { myk = ok; myj = oj; }
            }
        }
        {   // k=64, jj=32: lanes 0..31 <- the 32 smallest (unordered)
            const unsigned ok = (unsigned)__shfl_xor((int)myk, 32, 64);
            const unsigned oj = (unsigned)__shfl_xor((int)myj, 32, 64);
            const bool wantmin = ((lane & 32) == 0);
            const bool less = (myk < ok) || (myk == ok && myj < oj);
            if (less != wantmin) { myk = ok; myj = oj; }
        }

        // ---- epilogue: lane = channel e; max over the 32 selected ----
        float dx = 0.f, dy = 0.f, dz = 0.f;
        if (lane < KNN) {
            dx = s_x[myj] - px; dy = s_y[myj] - py; dz = s_z[myj] - pz;
        }
        const float basev = tbv + pbv + fmaf(pw2, pz, fmaf(pw1, py, pw0 * px));
        float mx = -3.0e38f;
        #pragma unroll
        for (int t = 0; t < KNN; ++t) {
            const float ndx = __builtin_bit_cast(float, __builtin_amdgcn_readlane(__builtin_bit_cast(int, dx), t));
            const float ndy = __builtin_bit_cast(float, __builtin_amdgcn_readlane(__builtin_bit_cast(int, dy), t));
            const float ndz = __builtin_bit_cast(float, __builtin_amdgcn_readlane(__builtin_bit_cast(int, dz), t));
            const float proj = fmaf(tw2, ndz, fmaf(tw1, ndy, tw0 * ndx));
            mx = fmaxf(mx, proj);
        }
        out[(((size_t)b * NPTS + (size_t)i) << 6) + lane] = mx + basev;
    }
}

extern "C" void kernel_launch(void* const* d_in, const int* in_sizes, int n_in,
                              void* d_out, int out_size, void* d_ws, size_t ws_size,
                              hipStream_t stream) {
    const float* x  = (const float*)d_in[0];
    const float* tw = (const float*)d_in[1];
    const float* tb = (const float*)d_in[2];
    const float* pw = (const float*)d_in[3];
    const float* pb = (const float*)d_in[4];
    float* out = (float*)d_out;

    dim3 grid(8 * 256);   // 2048 blocks x 16 pts (R16 verified geometry)
    dim3 block(512);
    hipLaunchKernelGGL(edgeconv_knn_kernel, grid, block, 0, stream,
                       x, tw, tb, pw, pb, out);
}

// Round 6
// 132.071 us; speedup vs baseline: 1.0793x; 1.0223x over previous
//
#include <hip/hip_runtime.h>

// EdgeConv with KNN graph: B=8, N=4096, D=3, E=64, K=32.
// === R22: R21 body (83.5 us verified) + speculative single-site compact ===
// R21 post-mortem: DPP lane-XORs WIN (86.4->83.5, VALUBusy 70->75% as
// predicted; ~half the chain latency was already TLP-hidden). Kept.
// R22: kill the initial cnt_lt(H) on the common path. Compaction's running
// `base` IS cnt_lt(H) (popc accumulated over all 64 ballots). H = sampled
// rank-32-of-64-minima -> c in [32,64] common; search is a no-op there.
// R17 tried this and spilled pk[] (TWO textual compact sites under
// divergent flow). R22 fix: ONE textual compact site inside a for(;;)
// retry loop -- speculate, break if c in [32,64]; else run the EXACT R16
// search (initial count = base, octave/bisect, L=0) and recompact once
// with final H, break unconditionally (preserves the H-L<=1 c>64 exit ->
// first-64-by-slot pool, R6 superset proof). Loop-carried pk[] across a
// backward branch == R16's cnt_lt-in-loop structure, which never spilled.
// Predicted: dur 83.5 -> 75-78 us (-~256 VALU cyc/pt of ~1170), VALUBusy
// 72-76%, VGPR 40-48, FETCH ~1.7MB, WRITE 8MB, occ ~51%.
// FAIL SIGNATURES: VGPR collapse + FETCH>>6MB = spill -> revert; null at
// 83 +/- 1 = count pass latency-hidden -> pivot to paired sweep.
// Unchanged: sweep math (BIT-IDENTICAL packed fmaf chain, self-dist == 0),
//  u16 monotone-truncation keys, PER-POINT sampled threshold, DPP lane-XOR
//  (xor1/2/8) bitonics, exact-fp32 partial bitonic, lower-index tie-break
//  == jax.lax.top_k, readlane epilogue, 2048x16 grid (512,6).
// SPILL DISCIPLINE (R2/R3): every loop touching pk[] FULLY unrolled, ONE
// textual instance of each; 85-VGPR budget. TRIPWIRE: FETCH>6MB.

#define NPTS 4096
#define KNN  32

#define WFENCE() __asm__ volatile("s_waitcnt lgkmcnt(0)" ::: "memory")

typedef unsigned short u16x2 __attribute__((ext_vector_type(2)));
typedef float          f32x2 __attribute__((ext_vector_type(2)));

__device__ __forceinline__ unsigned lane_prefix(unsigned long long m) {
    return __builtin_amdgcn_mbcnt_hi((unsigned)(m >> 32),
           __builtin_amdgcn_mbcnt_lo((unsigned)m, 0u));
}
__device__ __forceinline__ unsigned pk_min_u16(unsigned a, unsigned b) {
    return __builtin_bit_cast(unsigned, __builtin_elementwise_min(
        __builtin_bit_cast(u16x2, a), __builtin_bit_cast(u16x2, b)));
}
// lo16 = top16(d0), hi16 = top16(d1)
__device__ __forceinline__ unsigned pack_keys(float d0, float d1) {
    return __builtin_amdgcn_perm(__builtin_bit_cast(unsigned, d1),
                                 __builtin_bit_cast(unsigned, d0), 0x07060302u);
}

// Lane-XOR exchange. jj in {1,2,8}: DPP on the VALU pipe (quad_perm /
// row_ror:8) -- bit-exact permutation, no DS-pipe use, ~4cy latency.
// jj in {4,16,32}: fall back to __shfl_xor (ds_bpermute).
__device__ __forceinline__ unsigned lane_xor(unsigned v, const int jj) {
    if (jj == 1)
        return (unsigned)__builtin_amdgcn_update_dpp(
            (int)v, (int)v, 0xB1, 0xF, 0xF, false);   // quad_perm [1,0,3,2]
    if (jj == 2)
        return (unsigned)__builtin_amdgcn_update_dpp(
            (int)v, (int)v, 0x4E, 0xF, 0xF, false);   // quad_perm [2,3,0,1]
    if (jj == 8)
        return (unsigned)__builtin_amdgcn_update_dpp(
            (int)v, (int)v, 0x128, 0xF, 0xF, false);  // row_ror:8 == xor8
    return (unsigned)__shfl_xor((int)v, jj, 64);
}

__global__ __launch_bounds__(512, 6)
void edgeconv_knn_kernel(const float* __restrict__ x,
                         const float* __restrict__ theta_w,
                         const float* __restrict__ theta_b,
                         const float* __restrict__ phi_w,
                         const float* __restrict__ phi_b,
                         float* __restrict__ out)
{
    __shared__ float    s_x[NPTS];         // 16 KB per plane (48 KB total)
    __shared__ float    s_y[NPTS];
    __shared__ float    s_z[NPTS];
    __shared__ unsigned s_pool[8][64];     // 2 KB: per-wave survivor indices

    const int tid  = threadIdx.x;
    const int wv   = tid >> 6;
    const int lane = tid & 63;

    const int b  = blockIdx.x >> 8;        // 256 blocks per batch
    const int i0 = (blockIdx.x & 255) << 4;// 16 points per block (2 per wave)

    // lane == output channel e
    const float tw0 = theta_w[lane];
    const float tw1 = theta_w[64 + lane];
    const float tw2 = theta_w[128 + lane];
    const float tbv = theta_b[lane];
    const float pw0 = phi_w[lane];
    const float pw1 = phi_w[64 + lane];
    const float pw2 = phi_w[128 + lane];
    const float pbv = phi_b[lane];

    const float* xb = x + (size_t)b * NPTS * 3;
    for (int p = tid; p < NPTS; p += 512) {
        s_x[p] = xb[p * 3 + 0];
        s_y[p] = xb[p * 3 + 1];
        s_z[p] = xb[p * 3 + 2];
    }
    __syncthreads();

    for (int r = 0; r < 2; ++r) {
        const int i = i0 + wv * 2 + r;
        const float px = s_x[i], py = s_y[i], pz = s_z[i];
        const float sqi = fmaf(pz, pz, fmaf(py, py, px * px));
        const f32x2 PX2 = {px, px}, PY2 = {py, py}, PZ2 = {pz, pz};
        const f32x2 SQI2 = {sqi, sqi};
        const f32x2 N2   = {-2.0f, -2.0f};
        const f32x2 Z02  = {0.0f, 0.0f};

        // ---- sweep: lane owns candidates j = 256*t + 4*lane + {0..3} ----
        // slot s=0..63 -> j = ((s>>2)<<8) + (lane<<2) + (s&3)
        unsigned pk[32];
        unsigned pmin = 0xFFFFFFFFu;
        #pragma unroll
        for (int t = 0; t < 16; ++t) {
            const int jb = (t << 8) + (lane << 2);
            const float4 QX = *(const float4*)&s_x[jb];
            const float4 QY = *(const float4*)&s_y[jb];
            const float4 QZ = *(const float4*)&s_z[jb];
            const f32x2 X0 = {QX.x, QX.y}, X1 = {QX.z, QX.w};
            const f32x2 Y0 = {QY.x, QY.y}, Y1 = {QY.z, QY.w};
            const f32x2 Zc0 = {QZ.x, QZ.y}, Zc1 = {QZ.z, QZ.w};
            // sq_j with the identical chain: fma(z,z, fma(y,y, x*x))
            const f32x2 S0 = __builtin_elementwise_fma(Zc0, Zc0,
                             __builtin_elementwise_fma(Y0, Y0, X0 * X0));
            const f32x2 S1 = __builtin_elementwise_fma(Zc1, Zc1,
                             __builtin_elementwise_fma(Y1, Y1, X1 * X1));
            // dot with the identical chain: fma(pz,qz, fma(py,qy, px*qx))
            const f32x2 dt0 = __builtin_elementwise_fma(PZ2, Zc0,
                              __builtin_elementwise_fma(PY2, Y0, PX2 * X0));
            const f32x2 dt1 = __builtin_elementwise_fma(PZ2, Zc1,
                              __builtin_elementwise_fma(PY2, Y1, PX2 * X1));
            f32x2 d0 = __builtin_elementwise_fma(N2, dt0, SQI2 + S0);
            f32x2 d1 = __builtin_elementwise_fma(N2, dt1, SQI2 + S1);
            d0 = __builtin_elementwise_max(d0, Z02);
            d1 = __builtin_elementwise_max(d1, Z02);
            pk[2 * t]     = pack_keys(d0.x, d0.y);
            pk[2 * t + 1] = pack_keys(d1.x, d1.y);
            pmin = pk_min_u16(pmin, pk[2 * t]);
            pmin = pk_min_u16(pmin, pk[2 * t + 1]);
        }
        unsigned mn = min(pmin & 0xFFFFu, pmin >> 16);   // per-lane min (u16)

        // ---- PER-POINT bitonic sort of 64 lane-minima -> sampled threshold
        #pragma unroll
        for (int k = 2; k <= 64; k <<= 1) {
            #pragma unroll
            for (int jj = k >> 1; jj >= 1; jj >>= 1) {
                const unsigned o = lane_xor(mn, jj);
                const bool wantmin = (((lane & k) == 0) == ((lane & jj) == 0));
                const bool less = (mn < o);
                if (less != wantmin) mn = o;
            }
        }
        unsigned H = (unsigned)__builtin_amdgcn_readlane((int)mn, 32);

        // wave-uniform count of u16 keys strictly below T (ballot -> scalar)
        auto cnt_lt = [&](unsigned T) -> unsigned {
            unsigned c2 = 0;
            #pragma unroll
            for (int k2 = 0; k2 < 32; ++k2) {
                c2 += (unsigned)__popcll(__ballot((pk[k2] & 0xFFFFu) < T));
                c2 += (unsigned)__popcll(__ballot((pk[k2] >> 16)     < T));
            }
            return c2;
        };

        // ---- speculative compact with sampled H; ONE textual compact site --
        // base == cnt_lt(H) exactly (popc accumulated over all ballots).
        // Common case c in [32,64]: break, pool identical to count-then-
        // compact (search would be a no-op). Rare: exact R16 search, then
        // ONE recompact with final H (unconditional break preserves the
        // H-L<=1 c>64 exit -> first-64-by-slot pool, R6 proof).
        unsigned c = 0;
        {
            unsigned Lb = 0u;
            for (int attempt = 0; ; ++attempt) {
                WFENCE();                    // prior pool consumers done
                unsigned base = 0;
                #pragma unroll
                for (int s = 0; s < 64; ++s) {
                    const unsigned kk = (s & 1) ? (pk[s >> 1] >> 16)
                                                : (pk[s >> 1] & 0xFFFFu);
                    const bool pred = kk < H;
                    const unsigned long long bm = __ballot(pred);
                    if (bm) {
                        if (pred) {
                            const unsigned pos = base + lane_prefix(bm);
                            if (pos < 64u)
                                s_pool[wv][pos] = (unsigned)(((s >> 2) << 8)
                                                  + (lane << 2) + (s & 3));
                        }
                        base += (unsigned)__popcll(bm);
                    }
                }
                WFENCE();
                c = base;
                if (attempt > 0 || (c >= KNN && c <= 64u)) break;
                // rare path: exact R16 threshold search (c == cnt_lt(H))
                if (c < KNN) {               // raise by octaves (exp LSB 0x80)
                    unsigned step = 0x80u;
                    do {
                        unsigned Hn = H + step;
                        if (Hn > 0xFFFFu) Hn = 0xFFFFu;
                        Lb = H; H = Hn; step <<= 1;
                        c = cnt_lt(H);
                    } while (c < KNN);
                }
                while (c > 64u && (H - Lb) > 1u) {
                    const unsigned M  = Lb + ((H - Lb) >> 1);
                    const unsigned cm = cnt_lt(M);
                    if (cm >= KNN) { H = M; c = cm; } else { Lb = M; }
                }
            }
        }
        const unsigned m = c < 64u ? c : 64u;   // m >= 32 guaranteed

        // ---- exact fp32 keys for pool members (identical op chain) ----
        unsigned myk = 0xFFFFFFFFu;
        unsigned myj = 0u;                   // sentinel, never selected (m>=32)
        if ((unsigned)lane < m) {
            myj = s_pool[wv][lane];
            const float qx = s_x[myj], qy = s_y[myj], qz = s_z[myj];
            const float sqj = fmaf(qz, qz, fmaf(qy, qy, qx * qx));
            const float dt  = fmaf(pz, qz, fmaf(py, qy, px * qx));
            float d = fmaf(-2.0f, dt, sqi + sqj);
            d = fmaxf(d, 0.0f);
            myk = __builtin_bit_cast(unsigned, d);
        }

        // ---- partial bitonic: 32-sorts + one merge -> bottom-32 unordered ----
        #pragma unroll
        for (int k = 2; k <= 32; k <<= 1) {
            #pragma unroll
            for (int jj = k >> 1; jj >= 1; jj >>= 1) {
                const unsigned ok = lane_xor(myk, jj);
                const unsigned oj = lane_xor(myj, jj);
                const bool wantmin = (((lane & k) == 0) == ((lane & jj) == 0));
                const bool less = (myk < ok) || (myk == ok && myj < oj);
                if (less != wantmin) { myk = ok; myj = oj; }
            }
        }
        {   // k=64, jj=32: lanes 0..31 <- the 32 smallest (unordered)
            const unsigned ok = (unsigned)__shfl_xor((int)myk, 32, 64);
            const unsigned oj = (unsigned)__shfl_xor((int)myj, 32, 64);
            const bool wantmin = ((lane & 32) == 0);
            const bool less = (myk < ok) || (myk == ok && myj < oj);
            if (less != wantmin) { myk = ok; myj = oj; }
        }

        // ---- epilogue: lane = channel e; max over the 32 selected ----
        float dx = 0.f, dy = 0.f, dz = 0.f;
        if (lane < KNN) {
            dx = s_x[myj] - px; dy = s_y[myj] - py; dz = s_z[myj] - pz;
        }
        const float basev = tbv + pbv + fmaf(pw2, pz, fmaf(pw1, py, pw0 * px));
        float mx = -3.0e38f;
        #pragma unroll
        for (int t = 0; t < KNN; ++t) {
            const float ndx = __builtin_bit_cast(float, __builtin_amdgcn_readlane(__builtin_bit_cast(int, dx), t));
            const float ndy = __builtin_bit_cast(float, __builtin_amdgcn_readlane(__builtin_bit_cast(int, dy), t));
            const float ndz = __builtin_bit_cast(float, __builtin_amdgcn_readlane(__builtin_bit_cast(int, dz), t));
            const float proj = fmaf(tw2, ndz, fmaf(tw1, ndy, tw0 * ndx));
            mx = fmaxf(mx, proj);
        }
        out[(((size_t)b * NPTS + (size_t)i) << 6) + lane] = mx + basev;
    }
}

extern "C" void kernel_launch(void* const* d_in, const int* in_sizes, int n_in,
                              void* d_out, int out_size, void* d_ws, size_t ws_size,
                              hipStream_t stream) {
    const float* x  = (const float*)d_in[0];
    const float* tw = (const float*)d_in[1];
    const float* tb = (const float*)d_in[2];
    const float* pw = (const float*)d_in[3];
    const float* pb = (const float*)d_in[4];
    float* out = (float*)d_out;

    dim3 grid(8 * 256);   // 2048 blocks x 16 pts (R16 verified geometry)
    dim3 block(512);
    hipLaunchKernelGGL(edgeconv_knn_kernel, grid, block, 0, stream,
                       x, tw, tb, pw, pb, out);
}